// Round 1
// baseline (108.005 us; speedup 1.0000x reference)
//
#include <hip/hip_runtime.h>
#include <math.h>

#define KMAX   32
#define CIN    64
#define COUT   64
#define NKERN  27
constexpr float BN_EPS = 1e-5f;

// ---------------- kernel 0: zero the stats accumulator ----------------
__global__ void k_zero(float* stats) {
    stats[threadIdx.x] = 0.0f;   // 128 threads: [0..63]=sum, [64..127]=sumsq
}

// ---------------- kernel 1: gather-conv + 64x64 matmul + relu --------
// Writes pre-BN activations x into `xout` (= d_out), accumulates per-channel
// sum / sumsq into stats via one block-level reduction + 128 atomics/block.
__global__ __launch_bounds__(256) void k_conv(
    const float* __restrict__ inputs,      // [N, 64]
    const float* __restrict__ sw,          // [27, 64, 1]
    const float* __restrict__ dw,          // [64, 64]
    const float* __restrict__ bias,        // [1, 64]
    const int*   __restrict__ nn_count,    // [N]
    const int*   __restrict__ nn_index,    // [N, 32]
    const int*   __restrict__ filt_index,  // [N, 32]
    float*       __restrict__ xout,        // [N, 64]  pre-BN (relu'd)
    float*       __restrict__ stats)       // [128]
{
    __shared__ float sw_lds[NKERN * CIN];   // 6.75 KB
    __shared__ float dw_lds[CIN * COUT];    // 16 KB
    __shared__ float sp_lds[4][CIN];        // per-wave sp broadcast
    __shared__ float red[2][4][COUT];       // stats reduction

    const int tid = threadIdx.x;
    for (int i = tid; i < NKERN * CIN; i += 256) sw_lds[i] = sw[i];
    for (int i = tid; i < CIN * COUT; i += 256) dw_lds[i] = dw[i];
    __syncthreads();

    const int wave = tid >> 6;
    const int lane = tid & 63;
    const int PPW  = 16;                       // points per wave
    const int base = blockIdx.x * (4 * PPW) + wave * PPW;

    const float b = bias[lane];
    float sum = 0.0f, sumsq = 0.0f;

    for (int p = 0; p < PPW; ++p) {
        const int n   = base + p;
        const int cnt = nn_count[n];
        const int* __restrict__ ni = nn_index  + (size_t)n * KMAX;
        const int* __restrict__ fi = filt_index + (size_t)n * KMAX;

        float acc = 0.0f;
        for (int k = 0; k < cnt; ++k) {
            const int idx = ni[k];      // wave-uniform -> scalar load
            const int f   = fi[k];
            acc += inputs[(size_t)idx * CIN + lane] * sw_lds[f * CIN + lane];
        }
        const float sp = acc / (float)cnt;

        // broadcast sp across the wave via LDS (wave-lockstep: no barrier)
        sp_lds[wave][lane] = sp;
        float xv = b;
        #pragma unroll
        for (int c = 0; c < CIN; ++c)
            xv = fmaf(sp_lds[wave][c], dw_lds[c * COUT + lane], xv);
        xv = fmaxf(xv, 0.0f);

        xout[(size_t)n * COUT + lane] = xv;
        sum   += xv;
        sumsq += xv * xv;
    }

    red[0][wave][lane] = sum;
    red[1][wave][lane] = sumsq;
    __syncthreads();
    if (wave == 0) {
        float s = red[0][0][lane] + red[0][1][lane] + red[0][2][lane] + red[0][3][lane];
        float q = red[1][0][lane] + red[1][1][lane] + red[1][2][lane] + red[1][3][lane];
        atomicAdd(&stats[lane], s);
        atomicAdd(&stats[COUT + lane], q);
    }
}

// ---------------- kernel 2: finalize BN scale/shift -------------------
__global__ void k_finalize(const float* __restrict__ stats,
                           const float* __restrict__ gamma,
                           const float* __restrict__ beta,
                           float* __restrict__ sc_sh, float invN) {
    const int j = threadIdx.x;               // 64 threads
    const float mean = stats[j] * invN;
    const float var  = stats[COUT + j] * invN - mean * mean;
    const float s    = gamma[j] * rsqrtf(var + BN_EPS);
    sc_sh[j]        = s;
    sc_sh[COUT + j] = beta[j] - mean * s;
}

// ---------------- kernel 3: apply BN in place on d_out ----------------
__global__ __launch_bounds__(256) void k_apply(float* __restrict__ x,
                                               const float* __restrict__ sc_sh,
                                               int total4) {
    __shared__ float s[COUT], sh[COUT];
    if (threadIdx.x < COUT) {
        s[threadIdx.x]  = sc_sh[threadIdx.x];
        sh[threadIdx.x] = sc_sh[COUT + threadIdx.x];
    }
    __syncthreads();
    const int stride = gridDim.x * blockDim.x;
    for (int idx = blockIdx.x * blockDim.x + threadIdx.x; idx < total4; idx += stride) {
        float4 v = ((const float4*)x)[idx];
        const int j = (idx * 4) & (COUT - 1);  // COUT divisible by 4: j..j+3 in-row
        v.x = fmaf(v.x, s[j],     sh[j]);
        v.y = fmaf(v.y, s[j + 1], sh[j + 1]);
        v.z = fmaf(v.z, s[j + 2], sh[j + 2]);
        v.w = fmaf(v.w, s[j + 3], sh[j + 3]);
        ((float4*)x)[idx] = v;
    }
}

extern "C" void kernel_launch(void* const* d_in, const int* in_sizes, int n_in,
                              void* d_out, int out_size, void* d_ws, size_t ws_size,
                              hipStream_t stream) {
    const float* inputs     = (const float*)d_in[0];
    const float* sw         = (const float*)d_in[1];
    const float* dw         = (const float*)d_in[2];
    const float* bias       = (const float*)d_in[3];
    const float* gamma      = (const float*)d_in[4];
    const float* beta       = (const float*)d_in[5];
    const int*   nn_count   = (const int*)d_in[6];
    const int*   nn_index   = (const int*)d_in[7];
    const int*   filt_index = (const int*)d_in[8];

    const int N = in_sizes[0] / CIN;           // 65536
    float* x     = (float*)d_out;              // pre-BN activations, then final out
    float* stats = (float*)d_ws;               // 128 floats
    float* sc_sh = (float*)d_ws + 128;         // 128 floats

    k_zero<<<1, 128, 0, stream>>>(stats);

    const int pts_per_block = 64;              // 4 waves x 16 points
    k_conv<<<N / pts_per_block, 256, 0, stream>>>(
        inputs, sw, dw, bias, nn_count, nn_index, filt_index, x, stats);

    k_finalize<<<1, COUT, 0, stream>>>(stats, gamma, beta, sc_sh, 1.0f / (float)N);

    const int total4 = N * COUT / 4;
    k_apply<<<2048, 256, 0, stream>>>(x, sc_sh, total4);
}